// Round 1
// baseline (151.217 us; speedup 1.0000x reference)
//
#include <hip/hip_runtime.h>
#include <math.h>

// CantorAttention: B=2, S=2048, DIM=512, H=8, HD=64, K=64
#define B_    2
#define S_    2048
#define DIM_  512
#define H_    8
#define HD_   64
#define K_    64
#define M_    (B_ * S_)          // 4096
#define NQKV_ (3 * DIM_)         // 1536

typedef __attribute__((ext_vector_type(8))) _Float16       half8;     // mfma A/B frag (8 f16)
typedef __attribute__((ext_vector_type(2))) _Float16       half2v;    // fdot2 operand
typedef __attribute__((ext_vector_type(8))) unsigned short ushort8v;  // 16B move
typedef __attribute__((ext_vector_type(4))) float          float4v;   // mfma C/D frag

// ---- fp16 helpers ----------------------------------------------------------
__device__ __forceinline__ unsigned short f2h(float f) {
    _Float16 h = (_Float16)f;
    unsigned short u; __builtin_memcpy(&u, &h, 2); return u;
}
__device__ __forceinline__ float h2f(unsigned short u) {
    _Float16 h; __builtin_memcpy(&h, &u, 2); return (float)h;
}

// async 16B global -> LDS (lane l lands at ldsbase + l*16; global src is per-lane)
__device__ __forceinline__ void load_lds16(const unsigned short* g, unsigned short* l) {
    __builtin_amdgcn_global_load_lds(
        (const __attribute__((address_space(1))) void*)g,
        (__attribute__((address_space(3))) void*)l, 16, 0, 0);
}

// ---------------------------------------------------------------------------
// prep_all: one kernel, block-range partitioned.
//   [0,1024): convert x fp32 -> xh fp16 (8 elems/thread; 1-term scheme)
//   [1024,1792): transpose Wqkv -> Wqh fp16 [N][Kd] (48 x 16 tiles of 32x32)
//   [1792,2048): transpose Wout -> Woh fp16 (16 x 16 tiles)
// ---------------------------------------------------------------------------
__global__ __launch_bounds__(256) void prep_all(
    const float* __restrict__ X, unsigned short* __restrict__ Xh,
    const float* __restrict__ Wq, unsigned short* __restrict__ Wqh,
    const float* __restrict__ Wo, unsigned short* __restrict__ Woh)
{
    __shared__ float tile[32][33];
    const int bid = blockIdx.x, t = threadIdx.x;

    if (bid < 1024) {
        size_t i = ((size_t)bid * 256 + t) * 8;
        float4 a = *(const float4*)&X[i];
        float4 b = *(const float4*)&X[i + 4];
        float f[8] = {a.x, a.y, a.z, a.w, b.x, b.y, b.z, b.w};
        ushort8v h;
        #pragma unroll
        for (int j = 0; j < 8; ++j) h[j] = f2h(f[j]);
        *(ushort8v*)&Xh[i] = h;
        return;
    }

    const float* W;
    unsigned short* Whi;
    int N, k0, n0;
    if (bid < 1792) {
        int idx = bid - 1024;                  // 768 blocks: 48 n-tiles x 16 k-tiles
        W = Wq; Whi = Wqh; N = NQKV_;
        n0 = (idx % 48) * 32; k0 = (idx / 48) * 32;
    } else {
        int idx = bid - 1792;                  // 256 blocks: 16 x 16
        W = Wo; Whi = Woh; N = DIM_;
        n0 = (idx % 16) * 32; k0 = (idx / 16) * 32;
    }
    const int c = t & 31, r8 = t >> 5;
    #pragma unroll
    for (int i = 0; i < 4; ++i) {
        int r = r8 + i * 8;
        tile[r][c] = W[(size_t)(k0 + r) * N + n0 + c];
    }
    __syncthreads();
    #pragma unroll
    for (int i = 0; i < 4; ++i) {
        int r = r8 + i * 8;                 // n offset
        Whi[(size_t)(n0 + r) * 512 + k0 + c] = f2h(tile[c][r]);   // Kd = 512
    }
}

// ---------------------------------------------------------------------------
// group_routes: single block, 1024 threads. Exploits the Cantor structure:
// routes[s][0] == min{ j : c_j == c_s } (self-distance 0, stable argsort),
// so it is a PERFECT class key: rows sharing it have identical route rows.
// Builds: members[2048] (rows grouped by class) and chunk records
// (classLeader, memberStart, memberCnt<=8) + nChunks.
// ---------------------------------------------------------------------------
__global__ __launch_bounds__(1024) void group_routes(
    const int* __restrict__ routes, int* __restrict__ members,
    int4* __restrict__ recs, int* __restrict__ nch)
{
    __shared__ int cnt[2048];
    __shared__ int base[2048];
    __shared__ int cur[2048];
    __shared__ int sc[1024];
    const int t = threadIdx.x;
    const int s0 = 2 * t, s1 = 2 * t + 1;

    cnt[s0] = 0; cnt[s1] = 0;
    __syncthreads();

    const int l0 = routes[(size_t)s0 * K_];
    const int l1 = routes[(size_t)s1 * K_];
    atomicAdd(&cnt[l0], 1);
    atomicAdd(&cnt[l1], 1);
    __syncthreads();

    // exclusive scan of cnt -> base (pairwise + Hillis-Steele over 1024)
    const int c0 = cnt[s0], c1 = cnt[s1];
    int pair = c0 + c1;
    sc[t] = pair;
    __syncthreads();
    for (int off = 1; off < 1024; off <<= 1) {
        int v = sc[t];
        if (t >= off) v += sc[t - off];
        __syncthreads();
        sc[t] = v;
        __syncthreads();
    }
    int excl = sc[t] - pair;
    base[s0] = excl;
    base[s1] = excl + c0;
    cur[s0] = 0; cur[s1] = 0;
    __syncthreads();

    // scatter members grouped by class
    int pos0 = base[l0] + atomicAdd(&cur[l0], 1);
    members[pos0] = s0;
    int pos1 = base[l1] + atomicAdd(&cur[l1], 1);
    members[pos1] = s1;

    // chunk records: ceil(cnt/8) chunks per class
    const int cc0 = (c0 + 7) >> 3, cc1 = (c1 + 7) >> 3;
    int cpair = cc0 + cc1;
    __syncthreads();          // done reading sc from first scan
    sc[t] = cpair;
    __syncthreads();
    for (int off = 1; off < 1024; off <<= 1) {
        int v = sc[t];
        if (t >= off) v += sc[t - off];
        __syncthreads();
        sc[t] = v;
        __syncthreads();
    }
    int cex = sc[t] - cpair;
    for (int c = 0; c < cc0; ++c) {
        int rem = c0 - 8 * c;
        recs[cex + c] = make_int4(s0, base[s0] + 8 * c, rem < 8 ? rem : 8, 0);
    }
    for (int c = 0; c < cc1; ++c) {
        int rem = c1 - 8 * c;
        recs[cex + cc0 + c] = make_int4(s1, base[s1] + 8 * c, rem < 8 ? rem : 8, 0);
    }
    if (t == 1023) nch[0] = sc[1023];
}

// ---------------------------------------------------------------------------
// fp16 MFMA GEMM. TERMS=2: C=(Ah+Al)*Wh. TERMS=1: C=Ah*Wh (err ~2^-10).
// Double-buffered global_load_lds staging (prefetch a compute phase ahead).
//   mode 0: row-major fp32 C.
//   mode 1: qkv scatter -> Q/K/V all fp16, layout [B,H,S,HD].
// ---------------------------------------------------------------------------
template<int BM, int BN, int WM, int WN, int TERMS>
__global__ __launch_bounds__(256) void gemm_mfma(
    const unsigned short* __restrict__ Ahi, const unsigned short* __restrict__ Alo,
    const unsigned short* __restrict__ Wh,
    const float* __restrict__ bias, float* __restrict__ C,
    unsigned short* __restrict__ Qho, unsigned short* __restrict__ Kho,
    unsigned short* __restrict__ Vho,
    int N, int Kd, int mode)
{
    constexpr int TM = WM / 16, TN = WN / 16;
    constexpr int WAVES_N = BN / WN;
    __shared__ unsigned short Ah[2][BM][32];
    __shared__ unsigned short Al[TERMS == 2 ? 2 : 1][TERMS == 2 ? BM : 1][32];
    __shared__ unsigned short Bh[2][BN][32];

    const int t = threadIdx.x, lane = t & 63, wave = t >> 6;
    const int wm = (wave / WAVES_N) * WM, wn = (wave % WAVES_N) * WN;
    const int m0 = blockIdx.y * BM, n0 = blockIdx.x * BN;
    const int l15 = lane & 15, l4 = lane >> 4;

    const int srow = lane >> 2;          // 0..15
    const int scol = (lane & 3) * 8;     // 0,8,16,24

    float4v acc[TM][TN];
    #pragma unroll
    for (int i = 0; i < TM; ++i)
        #pragma unroll
        for (int j = 0; j < TN; ++j)
            #pragma unroll
            for (int r = 0; r < 4; ++r) acc[i][j][r] = 0.f;

    const int NK = Kd / 32;

    #pragma unroll
    for (int c = wave; c < BM / 16; c += 4) {
        size_t g = (size_t)(m0 + c * 16 + srow) * Kd + scol;
        load_lds16(&Ahi[g], &Ah[0][c * 16][0]);
        if constexpr (TERMS == 2) load_lds16(&Alo[g], &Al[0][c * 16][0]);
    }
    #pragma unroll
    for (int c = wave; c < BN / 16; c += 4) {
        size_t g = (size_t)(n0 + c * 16 + srow) * Kd + scol;
        load_lds16(&Wh[g], &Bh[0][c * 16][0]);
    }
    __syncthreads();

    for (int ks = 0; ks < NK; ++ks) {
        const int cur = ks & 1, nxt = cur ^ 1;

        if (ks + 1 < NK) {
            const int k1 = (ks + 1) * 32;
            #pragma unroll
            for (int c = wave; c < BM / 16; c += 4) {
                size_t g = (size_t)(m0 + c * 16 + srow) * Kd + k1 + scol;
                load_lds16(&Ahi[g], &Ah[nxt][c * 16][0]);
                if constexpr (TERMS == 2) load_lds16(&Alo[g], &Al[nxt][c * 16][0]);
            }
            #pragma unroll
            for (int c = wave; c < BN / 16; c += 4) {
                size_t g = (size_t)(n0 + c * 16 + srow) * Kd + k1 + scol;
                load_lds16(&Wh[g], &Bh[nxt][c * 16][0]);
            }
        }

        half8 fa_h[TM], fa_l[TM], fb[TN];
        #pragma unroll
        for (int im = 0; im < TM; ++im) {
            fa_h[im] = *(const half8*)&Ah[cur][wm + im * 16 + l15][l4 * 8];
            if constexpr (TERMS == 2)
                fa_l[im] = *(const half8*)&Al[cur][wm + im * 16 + l15][l4 * 8];
        }
        #pragma unroll
        for (int in = 0; in < TN; ++in)
            fb[in] = *(const half8*)&Bh[cur][wn + in * 16 + l15][l4 * 8];
        #pragma unroll
        for (int im = 0; im < TM; ++im)
            #pragma unroll
            for (int in = 0; in < TN; ++in) {
                acc[im][in] = __builtin_amdgcn_mfma_f32_16x16x32_f16(fa_h[im], fb[in], acc[im][in], 0, 0, 0);
                if constexpr (TERMS == 2)
                    acc[im][in] = __builtin_amdgcn_mfma_f32_16x16x32_f16(fa_l[im], fb[in], acc[im][in], 0, 0, 0);
            }

        __syncthreads();
    }

    // epilogue: D row = (lane>>4)*4 + reg, col = lane&15  [m89-verified layout]
    if (mode == 0) {
        #pragma unroll
        for (int in = 0; in < TN; ++in) {
            int n = n0 + wn + in * 16 + l15;
            float bv = bias[n];
            #pragma unroll
            for (int im = 0; im < TM; ++im) {
                int mb = m0 + wm + im * 16 + l4 * 4;
                #pragma unroll
                for (int r = 0; r < 4; ++r)
                    C[(size_t)(mb + r) * N + n] = acc[im][in][r] + bv;
            }
        }
    } else {
        #pragma unroll
        for (int in = 0; in < TN; ++in) {
            int n = n0 + wn + in * 16 + l15;
            int which = n >> 9, h = (n >> 6) & 7, d = n & 63;
            unsigned short* dst = (which == 0) ? Qho : (which == 1 ? Kho : Vho);
            float bv = bias[n];
            #pragma unroll
            for (int im = 0; im < TM; ++im) {
                int mb = m0 + wm + im * 16 + l4 * 4;
                #pragma unroll
                for (int r = 0; r < 4; ++r) {
                    int m = mb + r, b = m >> 11, s = m & 2047;
                    dst[(((size_t)b * H_ + h) * S_ + s) * HD_ + d] =
                        f2h(acc[im][in][r] + bv);
                }
            }
        }
    }
}

// ---------------------------------------------------------------------------
// Class-grouped gathered attention.
// All rows in a class share an IDENTICAL route row, so each block stages the
// class's 64 K-rows + 64 V-rows into LDS ONCE (16 KB) and amortizes it over
// up to 8 member rows (2 per wave, same swizzled fdot2/softmax pipeline as
// before but reading LDS). Gather traffic drops from 16 KB/row to
// 16 KB/chunk (~5x). Blocks loop over chunk slots (grid-stride, 256 slots
// per bh); bh->XCD mapping keeps each (b,h)'s K/V resident in one L2.
// ---------------------------------------------------------------------------
__global__ __launch_bounds__(256, 4) void attn_kernel(
    const unsigned short* __restrict__ Qh, const unsigned short* __restrict__ Kh,
    const unsigned short* __restrict__ Vh, const int* __restrict__ routes,
    const int* __restrict__ members, const int4* __restrict__ recs,
    const int* __restrict__ nchp,
    unsigned short* __restrict__ Oh)
{
    __shared__ unsigned short Kl[64 * 64];   // 8 KB, row-major [key][d]
    __shared__ unsigned short Vl[64 * 64];   // 8 KB

    const int t = threadIdx.x, wv = t >> 6, lane = t & 63;
    const int blk  = blockIdx.x;
    const int xcd  = blk & 7;
    const int half = (blk >> 3) & 1;
    const int slot = blk >> 4;            // [0, 256)
    const int bh   = xcd | (half << 3);   // [0, 16)
    const int b    = bh >> 3, h = bh & 7;

    const int p  = lane & 7;              // chunk (q/k) + pass selector
    const int jl = lane >> 3;             // key-in-pass
    const int kg = lane >> 3, p8 = lane & 7;

    const unsigned short* kbase = Kh + (size_t)bh * S_ * HD_;
    const unsigned short* vbase = Vh + (size_t)bh * S_ * HD_;
    const int nch = nchp[0];

    for (int chunk = slot; chunk < nch; chunk += 256) {
        const int4 rec = recs[chunk];
        const int leader = rec.x, mstart = rec.y, mcnt = rec.z;

        // per-wave copy of the class route list
        const int rl = routes[(size_t)leader * K_ + lane];

        // stage K,V: global_load_lds; pass i covers flat 16B-chunks
        // q = i*256 + wv*64 + lane  ->  key row q>>3, 16B col q&7.
        // LDS dest is wave-linear (base + lane*16); global src per-lane gather.
        #pragma unroll
        for (int i = 0; i < 2; ++i) {
            int row = i * 32 + wv * 8 + jl;
            int r = __shfl(rl, row);
            load_lds16(&kbase[(size_t)r * HD_ + p * 8], &Kl[(i * 256 + wv * 64) * 8]);
        }
        #pragma unroll
        for (int i = 0; i < 2; ++i) {
            int row = i * 32 + wv * 8 + jl;
            int r = __shfl(rl, row);
            load_lds16(&vbase[(size_t)r * HD_ + p * 8], &Vl[(i * 256 + wv * 64) * 8]);
        }
        __syncthreads();   // drains vmcnt (compiler-inserted) before LDS reads

        // wave wv handles members 2wv, 2wv+1 (clamped; stores guarded)
        const int i0 = 2 * wv, i1 = 2 * wv + 1;
        const bool v0 = i0 < mcnt, v1 = i1 < mcnt;
        const int s0 = members[mstart + (v0 ? i0 : 0)];
        const int s1 = members[mstart + (v1 ? i1 : 0)];

        // q loads: 16B chunk p of the member's q row
        ushort8v qv0u = *(const ushort8v*)&Qh[((size_t)bh * S_ + s0) * HD_ + p * 8];
        ushort8v qv1u = *(const ushort8v*)&Qh[((size_t)bh * S_ + s1) * HD_ + p * 8];
        half2v qp0[4], qp1[4];
        __builtin_memcpy(qp0, &qv0u, 16);
        __builtin_memcpy(qp1, &qv1u, 16);

        // scores: key j = pass*8+jl, q/k chunk p, reduce over p, keep pass==p
        float sc0 = 0.f, sc1 = 0.f;
        #pragma unroll
        for (int pass = 0; pass < 8; ++pass) {
            const int j = pass * 8 + jl;
            half2v kp[4];
            ushort8v kv = *(const ushort8v*)&Kl[j * 64 + p * 8];  // 1KB/wave, conflict-free
            __builtin_memcpy(kp, &kv, 16);
            float pa = 0.f, pb = 0.f;
            #pragma unroll
            for (int i = 0; i < 4; ++i) {
                pa = __builtin_amdgcn_fdot2(qp0[i], kp[i], pa, false);
                pb = __builtin_amdgcn_fdot2(qp1[i], kp[i], pb, false);
            }
            pa += __shfl_xor(pa, 1);  pb += __shfl_xor(pb, 1);
            pa += __shfl_xor(pa, 2);  pb += __shfl_xor(pb, 2);
            pa += __shfl_xor(pa, 4);  pb += __shfl_xor(pb, 4);
            if (pass == p) { sc0 = pa; sc1 = pb; }
        }
        sc0 *= 0.125f;  sc1 *= 0.125f;
        // lane L now holds score of key swap(L) = (L&7)*8 + (L>>3)

        // softmax (permutation-invariant across lanes)
        float ma = sc0, mb = sc1;
        #pragma unroll
        for (int off = 32; off >= 1; off >>= 1) {
            ma = fmaxf(ma, __shfl_xor(ma, off));
            mb = fmaxf(mb, __shfl_xor(mb, off));
        }
        float ea = __expf(sc0 - ma), eb = __expf(sc1 - mb);
        float su_a = ea, su_b = eb;
        #pragma unroll
        for (int off = 32; off >= 1; off >>= 1) {
            su_a += __shfl_xor(su_a, off);
            su_b += __shfl_xor(su_b, off);
        }
        const float w0 = ea / su_a, w1 = eb / su_b;

        // phase 2: weight of key i*8+kg lives in lane swap(i*8+kg) = kg*8+i
        float ac0[8] = {0.f,0.f,0.f,0.f,0.f,0.f,0.f,0.f};
        float ac1[8] = {0.f,0.f,0.f,0.f,0.f,0.f,0.f,0.f};
        #pragma unroll
        for (int i = 0; i < 8; ++i) {
            const int key = i * 8 + kg;
            float wj0 = __shfl(w0, kg * 8 + i), wj1 = __shfl(w1, kg * 8 + i);
            ushort8v vv = *(const ushort8v*)&Vl[key * 64 + p8 * 8];  // conflict-free
            #pragma unroll
            for (int j = 0; j < 8; ++j) {
                float vf = h2f(vv[j]);
                ac0[j] += wj0 * vf;
                ac1[j] += wj1 * vf;
            }
        }
        #pragma unroll
        for (int off = 8; off <= 32; off <<= 1) {
            #pragma unroll
            for (int j = 0; j < 8; ++j) {
                ac0[j] += __shfl_xor(ac0[j], off);
                ac1[j] += __shfl_xor(ac1[j], off);
            }
        }

        if (kg == 0) {
            ushort8v h0, h1;
            #pragma unroll
            for (int j = 0; j < 8; ++j) {
                h0[j] = f2h(ac0[j]);
                h1[j] = f2h(ac1[j]);
            }
            if (v0) {
                size_t oi0 = ((size_t)b * S_ + s0) * DIM_ + h * HD_ + p8 * 8;
                *(ushort8v*)&Oh[oi0] = h0;
            }
            if (v1) {
                size_t oi1 = ((size_t)b * S_ + s1) * DIM_ + h * HD_ + p8 * 8;
                *(ushort8v*)&Oh[oi1] = h1;
            }
        }
        __syncthreads();   // LDS reused next chunk iteration
    }
}

// ---------------------------------------------------------------------------
// ws layout (bytes):
//   0    Q fp16 4MB | 8M K fp16 4MB | 16M V fp16 4MB
//   24M  x_h / attn fp16 4MB
//   32M  Wqkv_h fp16 1.5M | +1.5M Wout_h fp16 0.5M
//   34M  members int[2048] (8KB) | +8K recs int4[2048] (32KB) | +40K nChunks
// ---------------------------------------------------------------------------
extern "C" void kernel_launch(void* const* d_in, const int* in_sizes, int n_in,
                              void* d_out, int out_size, void* d_ws, size_t ws_size,
                              hipStream_t stream)
{
    const float* x      = (const float*)d_in[0];
    const float* Wqkv   = (const float*)d_in[1];
    const float* bqkv   = (const float*)d_in[2];
    const float* Wout   = (const float*)d_in[3];
    const float* bout   = (const float*)d_in[4];
    const int*   routes = (const int*)d_in[5];
    float* out = (float*)d_out;

    char* w = (char*)d_ws;
    unsigned short* Qh = (unsigned short*)(w);
    unsigned short* Kh = (unsigned short*)(w + (8u << 20));
    unsigned short* Vh = (unsigned short*)(w + (16u << 20));
    unsigned short* xh = (unsigned short*)(w + (24u << 20));
    unsigned short* ah = xh;   // aliased: free after qkv gemm
    unsigned short* wqh = (unsigned short*)(w + (32u << 20));
    unsigned short* woh = (unsigned short*)(w + (32u << 20) + 1572864u);
    int*  members = (int*)(w + (34u << 20));
    int4* recs    = (int4*)(w + (34u << 20) + 8192u);
    int*  nchp    = (int*)(w + (34u << 20) + 8192u + 32768u);

    dim3 blk(256);

    // class grouping from routes (independent of everything else)
    group_routes<<<dim3(1), dim3(1024), 0, stream>>>(routes, members, recs, nchp);

    // fused prep: x-convert (1024 blocks) + Wqkv transpose (768) + Wout (256)
    prep_all<<<dim3(2048), blk, 0, stream>>>(x, xh, Wqkv, wqh, Wout, woh);

    // qkv: M=4096, N=1536, K=512 -> 16x32 = 512 blocks, 1-term A
    gemm_mfma<128, 96, 64, 48, 1><<<dim3(NQKV_ / 96, M_ / 128), blk, 0, stream>>>(
        xh, nullptr, wqh, bqkv, nullptr, Qh, Kh, Vh, NQKV_, DIM_, 1);

    attn_kernel<<<dim3(4096), blk, 0, stream>>>(Qh, Kh, Vh, routes, members, recs, nchp, ah);

    // out-proj: M=4096, N=512, K=512 -> 8x64 = 512 blocks, 1-term A
    gemm_mfma<64, 64, 32, 32, 1><<<dim3(DIM_ / 64, M_ / 64), blk, 0, stream>>>(
        ah, nullptr, woh, bout, out, nullptr, nullptr, nullptr, DIM_, DIM_, 0);
}

// Round 2
// 141.720 us; speedup vs baseline: 1.0670x; 1.0670x over previous
//
#include <hip/hip_runtime.h>
#include <math.h>

// CantorAttention: B=2, S=2048, DIM=512, H=8, HD=64, K=64
#define B_    2
#define S_    2048
#define DIM_  512
#define H_    8
#define HD_   64
#define K_    64
#define M_    (B_ * S_)          // 4096
#define NQKV_ (3 * DIM_)         // 1536

typedef __attribute__((ext_vector_type(8))) _Float16       half8;     // mfma A/B frag (8 f16)
typedef __attribute__((ext_vector_type(2))) _Float16       half2v;    // fdot2 operand
typedef __attribute__((ext_vector_type(8))) unsigned short ushort8v;  // 16B move
typedef __attribute__((ext_vector_type(4))) float          float4v;   // mfma C/D frag

// ---- fp16 helpers ----------------------------------------------------------
__device__ __forceinline__ unsigned short f2h(float f) {
    _Float16 h = (_Float16)f;
    unsigned short u; __builtin_memcpy(&u, &h, 2); return u;
}
__device__ __forceinline__ float h2f(unsigned short u) {
    _Float16 h; __builtin_memcpy(&h, &u, 2); return (float)h;
}

// ---- DPP reductions (VALU pipe; replaces ds_swizzle shuffles) --------------
// ctrl: 0xB1 = quad_perm[1,0,3,2] (xor1), 0x4E = quad_perm[2,3,0,1] (xor2),
//       0x141 = row_half_mirror (xor7), 0x140 = row_mirror (xor15).
// {xor1,xor2,xor7} is a complete butterfly over lane bits 0-2 for any
// commutative op; +{xor15} extends to bits 0-3.
template<int CTRL>
__device__ __forceinline__ float dpp_addf(float x) {
    int y = __builtin_amdgcn_update_dpp(0, __builtin_bit_cast(int, x),
                                        CTRL, 0xF, 0xF, true);
    return x + __builtin_bit_cast(float, y);
}
template<int CTRL>
__device__ __forceinline__ float dpp_maxf(float x) {
    int y = __builtin_amdgcn_update_dpp(0, __builtin_bit_cast(int, x),
                                        CTRL, 0xF, 0xF, true);
    return fmaxf(x, __builtin_bit_cast(float, y));
}

// async 16B global -> LDS (lane l lands at ldsbase + l*16)
__device__ __forceinline__ void load_lds16(const unsigned short* g, unsigned short* l) {
    __builtin_amdgcn_global_load_lds(
        (const __attribute__((address_space(1))) void*)g,
        (__attribute__((address_space(3))) void*)l, 16, 0, 0);
}

// ---------------------------------------------------------------------------
// prep_all: one kernel, block-range partitioned.
//   [0,1024): convert x fp32 -> xh fp16 (8 elems/thread; 1-term scheme)
//   [1024,1792): transpose Wqkv -> Wqh fp16 [N][Kd] (48 x 16 tiles of 32x32)
//   [1792,2048): transpose Wout -> Woh fp16 (16 x 16 tiles)
// ---------------------------------------------------------------------------
__global__ __launch_bounds__(256) void prep_all(
    const float* __restrict__ X, unsigned short* __restrict__ Xh,
    const float* __restrict__ Wq, unsigned short* __restrict__ Wqh,
    const float* __restrict__ Wo, unsigned short* __restrict__ Woh)
{
    __shared__ float tile[32][33];
    const int bid = blockIdx.x, t = threadIdx.x;

    if (bid < 1024) {
        size_t i = ((size_t)bid * 256 + t) * 8;
        float4 a = *(const float4*)&X[i];
        float4 b = *(const float4*)&X[i + 4];
        float f[8] = {a.x, a.y, a.z, a.w, b.x, b.y, b.z, b.w};
        ushort8v h;
        #pragma unroll
        for (int j = 0; j < 8; ++j) h[j] = f2h(f[j]);
        *(ushort8v*)&Xh[i] = h;
        return;
    }

    const float* W;
    unsigned short* Whi;
    int N, k0, n0;
    if (bid < 1792) {
        int idx = bid - 1024;                  // 768 blocks: 48 n-tiles x 16 k-tiles
        W = Wq; Whi = Wqh; N = NQKV_;
        n0 = (idx % 48) * 32; k0 = (idx / 48) * 32;
    } else {
        int idx = bid - 1792;                  // 256 blocks: 16 x 16
        W = Wo; Whi = Woh; N = DIM_;
        n0 = (idx % 16) * 32; k0 = (idx / 16) * 32;
    }
    const int c = t & 31, r8 = t >> 5;
    #pragma unroll
    for (int i = 0; i < 4; ++i) {
        int r = r8 + i * 8;
        tile[r][c] = W[(size_t)(k0 + r) * N + n0 + c];
    }
    __syncthreads();
    #pragma unroll
    for (int i = 0; i < 4; ++i) {
        int r = r8 + i * 8;                 // n offset
        Whi[(size_t)(n0 + r) * 512 + k0 + c] = f2h(tile[c][r]);   // Kd = 512
    }
}

// ---------------------------------------------------------------------------
// fp16 MFMA GEMM. TERMS=2: C=(Ah+Al)*Wh. TERMS=1: C=Ah*Wh (err ~2^-10).
// Double-buffered global_load_lds staging (prefetch a compute phase ahead).
//   mode 0: row-major fp32 C.
//   mode 1: qkv scatter -> Q/K/V all fp16, layout [B,H,S,HD].
// ---------------------------------------------------------------------------
template<int BM, int BN, int WM, int WN, int TERMS>
__global__ __launch_bounds__(256) void gemm_mfma(
    const unsigned short* __restrict__ Ahi, const unsigned short* __restrict__ Alo,
    const unsigned short* __restrict__ Wh,
    const float* __restrict__ bias, float* __restrict__ C,
    unsigned short* __restrict__ Qho, unsigned short* __restrict__ Kho,
    unsigned short* __restrict__ Vho,
    int N, int Kd, int mode)
{
    constexpr int TM = WM / 16, TN = WN / 16;
    constexpr int WAVES_N = BN / WN;
    __shared__ unsigned short Ah[2][BM][32];
    __shared__ unsigned short Al[TERMS == 2 ? 2 : 1][TERMS == 2 ? BM : 1][32];
    __shared__ unsigned short Bh[2][BN][32];

    const int t = threadIdx.x, lane = t & 63, wave = t >> 6;
    const int wm = (wave / WAVES_N) * WM, wn = (wave % WAVES_N) * WN;
    const int m0 = blockIdx.y * BM, n0 = blockIdx.x * BN;
    const int l15 = lane & 15, l4 = lane >> 4;

    const int srow = lane >> 2;          // 0..15
    const int scol = (lane & 3) * 8;     // 0,8,16,24

    float4v acc[TM][TN];
    #pragma unroll
    for (int i = 0; i < TM; ++i)
        #pragma unroll
        for (int j = 0; j < TN; ++j)
            #pragma unroll
            for (int r = 0; r < 4; ++r) acc[i][j][r] = 0.f;

    const int NK = Kd / 32;

    #pragma unroll
    for (int c = wave; c < BM / 16; c += 4) {
        size_t g = (size_t)(m0 + c * 16 + srow) * Kd + scol;
        load_lds16(&Ahi[g], &Ah[0][c * 16][0]);
        if constexpr (TERMS == 2) load_lds16(&Alo[g], &Al[0][c * 16][0]);
    }
    #pragma unroll
    for (int c = wave; c < BN / 16; c += 4) {
        size_t g = (size_t)(n0 + c * 16 + srow) * Kd + scol;
        load_lds16(&Wh[g], &Bh[0][c * 16][0]);
    }
    __syncthreads();

    for (int ks = 0; ks < NK; ++ks) {
        const int cur = ks & 1, nxt = cur ^ 1;

        if (ks + 1 < NK) {
            const int k1 = (ks + 1) * 32;
            #pragma unroll
            for (int c = wave; c < BM / 16; c += 4) {
                size_t g = (size_t)(m0 + c * 16 + srow) * Kd + k1 + scol;
                load_lds16(&Ahi[g], &Ah[nxt][c * 16][0]);
                if constexpr (TERMS == 2) load_lds16(&Alo[g], &Al[nxt][c * 16][0]);
            }
            #pragma unroll
            for (int c = wave; c < BN / 16; c += 4) {
                size_t g = (size_t)(n0 + c * 16 + srow) * Kd + k1 + scol;
                load_lds16(&Wh[g], &Bh[nxt][c * 16][0]);
            }
        }

        half8 fa_h[TM], fa_l[TM], fb[TN];
        #pragma unroll
        for (int im = 0; im < TM; ++im) {
            fa_h[im] = *(const half8*)&Ah[cur][wm + im * 16 + l15][l4 * 8];
            if constexpr (TERMS == 2)
                fa_l[im] = *(const half8*)&Al[cur][wm + im * 16 + l15][l4 * 8];
        }
        #pragma unroll
        for (int in = 0; in < TN; ++in)
            fb[in] = *(const half8*)&Bh[cur][wn + in * 16 + l15][l4 * 8];
        #pragma unroll
        for (int im = 0; im < TM; ++im)
            #pragma unroll
            for (int in = 0; in < TN; ++in) {
                acc[im][in] = __builtin_amdgcn_mfma_f32_16x16x32_f16(fa_h[im], fb[in], acc[im][in], 0, 0, 0);
                if constexpr (TERMS == 2)
                    acc[im][in] = __builtin_amdgcn_mfma_f32_16x16x32_f16(fa_l[im], fb[in], acc[im][in], 0, 0, 0);
            }

        __syncthreads();
    }

    // epilogue: D row = (lane>>4)*4 + reg, col = lane&15  [m89-verified layout]
    if (mode == 0) {
        #pragma unroll
        for (int in = 0; in < TN; ++in) {
            int n = n0 + wn + in * 16 + l15;
            float bv = bias[n];
            #pragma unroll
            for (int im = 0; im < TM; ++im) {
                int mb = m0 + wm + im * 16 + l4 * 4;
                #pragma unroll
                for (int r = 0; r < 4; ++r)
                    C[(size_t)(mb + r) * N + n] = acc[im][in][r] + bv;
            }
        }
    } else {
        #pragma unroll
        for (int in = 0; in < TN; ++in) {
            int n = n0 + wn + in * 16 + l15;
            int which = n >> 9, h = (n >> 6) & 7, d = n & 63;
            unsigned short* dst = (which == 0) ? Qho : (which == 1 ? Kho : Vho);
            float bv = bias[n];
            #pragma unroll
            for (int im = 0; im < TM; ++im) {
                int mb = m0 + wm + im * 16 + l4 * 4;
                #pragma unroll
                for (int r = 0; r < 4; ++r) {
                    int m = mb + r, b = m >> 11, s = m & 2047;
                    dst[(((size_t)b * H_ + h) * S_ + s) * HD_ + d] =
                        f2h(acc[im][in][r] + bv);
                }
            }
        }
    }
}

// ---------------------------------------------------------------------------
// Gathered attention — barrier-free / LDS-free, DS-pipe-minimized.
// Round-1 post-mortem: both prior versions were bound by ~170 ds_swizzle/
// ds_bpermute ops per 2-row wave chunk (dependent shuffle chains), not by
// L2 bandwidth. This version:
//   * phase-1 score reduce over lane bits 0-2 via DPP adds (0 DS ops)
//   * softmax 64-lane reduce: DPP for bits 0-3, shfl only for bits 4-5
//   * phase-2 ROLE SWAP: lane (p=lane&7, jl=lane>>3) accumulates d-chunk jl
//     over keys {i*8+p}, so the output reduce runs over bits 0-2 -> DPP,
//     killing the old 48-DS-op tree. Weight of key i*8+p sits at lane p*8+i
//     (8 bpermutes/row, unavoidable all-to-all).
//   * route entries loaded straight from L2 (no r-broadcast shuffles)
//   * K batch (16x16B) and V batch (16x16B) pinned via empty asm so they are
//     register-resident (prior VGPR=64 proved the compiler sank them,
//     serializing L2 round trips). V issued mid-phase-1 to overlap latency.
// DS ops per 2-row chunk: ~170 -> ~24.
// ---------------------------------------------------------------------------
__global__ __launch_bounds__(256, 4) void attn_kernel(
    const unsigned short* __restrict__ Qh, const unsigned short* __restrict__ Kh,
    const unsigned short* __restrict__ Vh, const int* __restrict__ routes,
    unsigned short* __restrict__ Oh)
{
    const int wv = threadIdx.x >> 6, lane = threadIdx.x & 63;

    const int blk  = blockIdx.x;
    const int xcd  = blk & 7;
    const int idx  = blk >> 3;            // [0, 512)
    const int half = idx >> 8;            // 0 or 1
    const int sblk = idx & 255;           // [0, 256)
    const int bh   = xcd | (half << 3);   // [0, 16)
    const int s0   = sblk * 8 + wv * 2;   // this wave: s0, s0+1
    const int b    = bh >> 3, h = bh & 7;

    const int p  = lane & 7;              // d-chunk (ph1) / key-subsel (ph2)
    const int jl = lane >> 3;             // key-in-pass (ph1) / d-chunk (ph2)

    const unsigned short* kbase = Kh + (size_t)bh * S_ * HD_;
    const unsigned short* vbase = Vh + (size_t)bh * S_ * HD_;
    const int* rb0 = routes + (size_t)s0 * K_;
    const int* rb1 = rb0 + K_;

    // q chunks (8 distinct 16B addrs per wave, broadcast)
    ushort8v qv0u = *(const ushort8v*)&Qh[((size_t)bh * S_ + s0) * HD_ + p * 8];
    ushort8v qv1u = *(const ushort8v*)&Qh[((size_t)bh * S_ + s0 + 1) * HD_ + p * 8];
    half2v qp0[4], qp1[4];
    __builtin_memcpy(qp0, &qv0u, 16);
    __builtin_memcpy(qp1, &qv1u, 16);

    // phase-2 route entries (key = i*8+p), issued early so V gathers can
    // fire mid-phase-1. 8 consecutive ints per instr -> 1 line.
    int r2a[8], r2b[8];
    #pragma unroll
    for (int i = 0; i < 8; ++i) { r2a[i] = rb0[i * 8 + p]; r2b[i] = rb1[i * 8 + p]; }

    // phase-1: route entry (key = pass*8+jl) then the K-row chunk.
    // 8 lanes share each row -> 128B coalesced segments.
    ushort8v k0a[8], k1a[8];
    #pragma unroll
    for (int pass = 0; pass < 8; ++pass) {
        int ra = rb0[pass * 8 + jl], rbv = rb1[pass * 8 + jl];
        k0a[pass] = *(const ushort8v*)&kbase[(size_t)ra * HD_ + p * 8];
        k1a[pass] = *(const ushort8v*)&kbase[(size_t)rbv * HD_ + p * 8];
    }
    #pragma unroll
    for (int i = 0; i < 8; ++i) {
        asm volatile("" : "+v"(k0a[i]));
        asm volatile("" : "+v"(k1a[i]));
    }

    // phase-1b: fdot2 partials + DPP reduce over bits 0-2; keep at pass==p.
    // Lane L ends with score of key swap(L) = (L&7)*8 + (L>>3).
    float sc0 = 0.f, sc1 = 0.f;
    ushort8v pv0[8], pv1[8];
    #pragma unroll
    for (int pass = 0; pass < 8; ++pass) {
        half2v kp0[4], kp1[4];
        __builtin_memcpy(kp0, &k0a[pass], 16);
        __builtin_memcpy(kp1, &k1a[pass], 16);
        float pa = 0.f, pb = 0.f;
        #pragma unroll
        for (int i = 0; i < 4; ++i) {
            pa = __builtin_amdgcn_fdot2(qp0[i], kp0[i], pa, false);
            pb = __builtin_amdgcn_fdot2(qp1[i], kp1[i], pb, false);
        }
        pa = dpp_addf<0xB1>(pa);   pb = dpp_addf<0xB1>(pb);
        pa = dpp_addf<0x4E>(pa);   pb = dpp_addf<0x4E>(pb);
        pa = dpp_addf<0x141>(pa);  pb = dpp_addf<0x141>(pb);
        if (pass == p) { sc0 = pa; sc1 = pb; }
        if (pass == 3) {
            // issue V gathers (chunk jl of key i*8+p) while phase-1 drains;
            // K regs for passes 0-3 are dead by here, so pv fits the budget.
            #pragma unroll
            for (int i = 0; i < 8; ++i) {
                pv0[i] = *(const ushort8v*)&vbase[(size_t)r2a[i] * HD_ + jl * 8];
                pv1[i] = *(const ushort8v*)&vbase[(size_t)r2b[i] * HD_ + jl * 8];
            }
        }
    }
    #pragma unroll
    for (int i = 0; i < 8; ++i) {
        asm volatile("" : "+v"(pv0[i]));
        asm volatile("" : "+v"(pv1[i]));
    }

    sc0 *= 0.125f;  sc1 *= 0.125f;

    // softmax over 64 lanes (scores are lane-permuted; softmax is
    // permutation-invariant): DPP bits 0-3, shfl bits 4-5.
    float ma = sc0, mb = sc1;
    ma = dpp_maxf<0xB1>(ma);   mb = dpp_maxf<0xB1>(mb);
    ma = dpp_maxf<0x4E>(ma);   mb = dpp_maxf<0x4E>(mb);
    ma = dpp_maxf<0x141>(ma);  mb = dpp_maxf<0x141>(mb);
    ma = dpp_maxf<0x140>(ma);  mb = dpp_maxf<0x140>(mb);
    ma = fmaxf(ma, __shfl_xor(ma, 16));  mb = fmaxf(mb, __shfl_xor(mb, 16));
    ma = fmaxf(ma, __shfl_xor(ma, 32));  mb = fmaxf(mb, __shfl_xor(mb, 32));
    float ea = __expf(sc0 - ma), eb = __expf(sc1 - mb);
    float sa = ea, sb = eb;
    sa = dpp_addf<0xB1>(sa);   sb = dpp_addf<0xB1>(sb);
    sa = dpp_addf<0x4E>(sa);   sb = dpp_addf<0x4E>(sb);
    sa = dpp_addf<0x141>(sa);  sb = dpp_addf<0x141>(sb);
    sa = dpp_addf<0x140>(sa);  sb = dpp_addf<0x140>(sb);
    sa += __shfl_xor(sa, 16);  sb += __shfl_xor(sb, 16);
    sa += __shfl_xor(sa, 32);  sb += __shfl_xor(sb, 32);
    const float w0 = ea / sa, w1 = eb / sb;   // weight of key swap(lane)

    // phase-2: lane accumulates d-chunk jl over keys {i*8+p}.
    // Weight of key i*8+p lives at lane p*8+i (swap inverse).
    float ac0[8] = {0.f,0.f,0.f,0.f,0.f,0.f,0.f,0.f};
    float ac1[8] = {0.f,0.f,0.f,0.f,0.f,0.f,0.f,0.f};
    #pragma unroll
    for (int i = 0; i < 8; ++i) {
        float wj0 = __shfl(w0, p * 8 + i);
        float wj1 = __shfl(w1, p * 8 + i);
        #pragma unroll
        for (int j = 0; j < 8; ++j) {
            ac0[j] += wj0 * h2f(pv0[i][j]);
            ac1[j] += wj1 * h2f(pv1[i][j]);
        }
    }
    // output reduce over key-subsel p (bits 0-2) -> pure DPP, no DS ops
    #pragma unroll
    for (int j = 0; j < 8; ++j) {
        ac0[j] = dpp_addf<0xB1>(ac0[j]);   ac1[j] = dpp_addf<0xB1>(ac1[j]);
        ac0[j] = dpp_addf<0x4E>(ac0[j]);   ac1[j] = dpp_addf<0x4E>(ac1[j]);
        ac0[j] = dpp_addf<0x141>(ac0[j]);  ac1[j] = dpp_addf<0x141>(ac1[j]);
    }

    if (p == 0) {   // 8 lanes store 8 contiguous 16B chunks = 128B row
        ushort8v h0, h1;
        #pragma unroll
        for (int j = 0; j < 8; ++j) {
            h0[j] = f2h(ac0[j]);
            h1[j] = f2h(ac1[j]);
        }
        size_t oi0 = ((size_t)b * S_ + s0) * DIM_ + h * HD_ + jl * 8;
        *(ushort8v*)&Oh[oi0] = h0;
        *(ushort8v*)&Oh[oi0 + DIM_] = h1;
    }
}

// ---------------------------------------------------------------------------
// ws layout (bytes):
//   0    Q fp16 4MB | 8M K fp16 4MB | 16M V fp16 4MB
//   24M  x_h / attn fp16 4MB
//   32M  Wqkv_h fp16 1.5M | +1.5M Wout_h fp16 0.5M
// ---------------------------------------------------------------------------
extern "C" void kernel_launch(void* const* d_in, const int* in_sizes, int n_in,
                              void* d_out, int out_size, void* d_ws, size_t ws_size,
                              hipStream_t stream)
{
    const float* x      = (const float*)d_in[0];
    const float* Wqkv   = (const float*)d_in[1];
    const float* bqkv   = (const float*)d_in[2];
    const float* Wout   = (const float*)d_in[3];
    const float* bout   = (const float*)d_in[4];
    const int*   routes = (const int*)d_in[5];
    float* out = (float*)d_out;

    char* w = (char*)d_ws;
    unsigned short* Qh = (unsigned short*)(w);
    unsigned short* Kh = (unsigned short*)(w + (8u << 20));
    unsigned short* Vh = (unsigned short*)(w + (16u << 20));
    unsigned short* xh = (unsigned short*)(w + (24u << 20));
    unsigned short* ah = xh;   // aliased: free after qkv gemm
    unsigned short* wqh = (unsigned short*)(w + (32u << 20));
    unsigned short* woh = (unsigned short*)(w + (32u << 20) + 1572864u);

    dim3 blk(256);

    // fused prep: x-convert (1024 blocks) + Wqkv transpose (768) + Wout (256)
    prep_all<<<dim3(2048), blk, 0, stream>>>(x, xh, Wqkv, wqh, Wout, woh);

    // qkv: M=4096, N=1536, K=512 -> 16x32 = 512 blocks, 1-term A
    gemm_mfma<128, 96, 64, 48, 1><<<dim3(NQKV_ / 96, M_ / 128), blk, 0, stream>>>(
        xh, nullptr, wqh, bqkv, nullptr, Qh, Kh, Vh, NQKV_, DIM_, 1);

    attn_kernel<<<dim3((B_ * H_ * S_) / 8), blk, 0, stream>>>(Qh, Kh, Vh, routes, ah);

    // out-proj: M=4096, N=512, K=512 -> 8x64 = 512 blocks, 1-term A
    gemm_mfma<64, 64, 32, 32, 1><<<dim3(DIM_ / 64, M_ / 64), blk, 0, stream>>>(
        ah, nullptr, woh, bout, out, nullptr, nullptr, nullptr, DIM_, DIM_, 0);
}

// Round 3
// 132.697 us; speedup vs baseline: 1.1396x; 1.0680x over previous
//
#include <hip/hip_runtime.h>
#include <math.h>

// CantorAttention: B=2, S=2048, DIM=512, H=8, HD=64, K=64
#define B_    2
#define S_    2048
#define DIM_  512
#define H_    8
#define HD_   64
#define K_    64
#define M_    (B_ * S_)          // 4096
#define NQKV_ (3 * DIM_)         // 1536

typedef __attribute__((ext_vector_type(8))) _Float16       half8;     // mfma A/B frag (8 f16)
typedef __attribute__((ext_vector_type(2))) _Float16       half2v;    // fdot2 operand
typedef __attribute__((ext_vector_type(8))) unsigned short ushort8v;  // 16B move
typedef __attribute__((ext_vector_type(4))) float          float4v;   // mfma C/D frag

// ---- fp16 helpers ----------------------------------------------------------
__device__ __forceinline__ unsigned short f2h(float f) {
    _Float16 h = (_Float16)f;
    unsigned short u; __builtin_memcpy(&u, &h, 2); return u;
}
__device__ __forceinline__ float h2f(unsigned short u) {
    _Float16 h; __builtin_memcpy(&h, &u, 2); return (float)h;
}

// ---- DPP reductions (VALU pipe) --------------------------------------------
// 0xB1 = quad_perm xor1, 0x4E = quad_perm xor2, 0x141 = row_half_mirror
// (completes bits 0-2), 0x140 = row_mirror (bit 3). Validated round 2.
template<int CTRL>
__device__ __forceinline__ float dpp_addf(float x) {
    int y = __builtin_amdgcn_update_dpp(0, __builtin_bit_cast(int, x),
                                        CTRL, 0xF, 0xF, true);
    return x + __builtin_bit_cast(float, y);
}
template<int CTRL>
__device__ __forceinline__ float dpp_maxf(float x) {
    int y = __builtin_amdgcn_update_dpp(0, __builtin_bit_cast(int, x),
                                        CTRL, 0xF, 0xF, true);
    return fmaxf(x, __builtin_bit_cast(float, y));
}

// async 16B global -> LDS (lane l lands at ldsbase + l*16)
__device__ __forceinline__ void load_lds16(const unsigned short* g, unsigned short* l) {
    __builtin_amdgcn_global_load_lds(
        (const __attribute__((address_space(1))) void*)g,
        (__attribute__((address_space(3))) void*)l, 16, 0, 0);
}

// ---------------------------------------------------------------------------
// prep_all: one kernel, block-range partitioned.
//   [0,1024): convert x fp32 -> xh fp16
//   [1024,1792): transpose Wqkv -> fp16 [N][Kd]
//   [1792,2048): transpose Wout -> fp16
//   [2048]: route class grouping (one 256-thread block; runs concurrently
//           with the other prep blocks, so ~free — unlike round 1's serial
//           1-block kernel). routes[s][0] is a perfect class key
//           (self-distance 0 + stable argsort), validated in round 1.
// ---------------------------------------------------------------------------
__global__ __launch_bounds__(256) void prep_all(
    const float* __restrict__ X, unsigned short* __restrict__ Xh,
    const float* __restrict__ Wq, unsigned short* __restrict__ Wqh,
    const float* __restrict__ Wo, unsigned short* __restrict__ Woh,
    const int* __restrict__ routes, int* __restrict__ members,
    int4* __restrict__ recs, int* __restrict__ nchp)
{
    __shared__ int smem[2048 * 3 + 256];     // 25.0 KB; aliased as fp tile too
    const int bid = blockIdx.x, t = threadIdx.x;

    if (bid < 1024) {
        size_t i = ((size_t)bid * 256 + t) * 8;
        float4 a = *(const float4*)&X[i];
        float4 b = *(const float4*)&X[i + 4];
        float f[8] = {a.x, a.y, a.z, a.w, b.x, b.y, b.z, b.w};
        ushort8v h;
        #pragma unroll
        for (int j = 0; j < 8; ++j) h[j] = f2h(f[j]);
        *(ushort8v*)&Xh[i] = h;
        return;
    }

    if (bid == 2048) {
        int* cnt  = smem;            // [2048] per-leader member count
        int* base = smem + 2048;     // [2048] member segment start
        int* cur  = smem + 4096;     // [2048] scatter cursor
        int* ps   = smem + 6144;     // [256]  scan workspace
        for (int i = t; i < 2048; i += 256) cnt[i] = 0;
        __syncthreads();
        int lead[8];
        #pragma unroll
        for (int i = 0; i < 8; ++i) {
            lead[i] = routes[(size_t)(i * 256 + t) * K_];
            atomicAdd(&cnt[lead[i]], 1);
        }
        __syncthreads();
        // scan 1: member bases (thread t owns classes [8t, 8t+8))
        int loc[8], sum = 0;
        #pragma unroll
        for (int i = 0; i < 8; ++i) { loc[i] = sum; sum += cnt[t * 8 + i]; }
        ps[t] = sum;
        __syncthreads();
        for (int off = 1; off < 256; off <<= 1) {
            int v = ps[t];
            if (t >= off) v += ps[t - off];
            __syncthreads(); ps[t] = v; __syncthreads();
        }
        const int excl = ps[t] - sum;
        #pragma unroll
        for (int i = 0; i < 8; ++i) { base[t * 8 + i] = excl + loc[i]; cur[t * 8 + i] = 0; }
        __syncthreads();
        #pragma unroll
        for (int i = 0; i < 8; ++i) {
            int s = i * 256 + t;
            members[base[lead[i]] + atomicAdd(&cur[lead[i]], 1)] = s;
        }
        // scan 2: chunk records (ceil(cnt/8) per class)
        int cloc[8], csum = 0;
        #pragma unroll
        for (int i = 0; i < 8; ++i) { cloc[i] = csum; csum += (cnt[t * 8 + i] + 7) >> 3; }
        __syncthreads();
        ps[t] = csum;
        __syncthreads();
        for (int off = 1; off < 256; off <<= 1) {
            int v = ps[t];
            if (t >= off) v += ps[t - off];
            __syncthreads(); ps[t] = v; __syncthreads();
        }
        const int cexcl = ps[t] - csum;
        #pragma unroll
        for (int i = 0; i < 8; ++i) {
            const int c = t * 8 + i, n = cnt[c];
            int w0 = cexcl + cloc[i];
            for (int k = 0; k * 8 < n; ++k) {
                int rem = n - k * 8;
                recs[w0 + k] = make_int4(c, base[c] + k * 8, rem < 8 ? rem : 8, 0);
            }
        }
        if (t == 255) nchp[0] = ps[255];
        return;
    }

    // weight transposes
    float (*tile)[33] = (float (*)[33])smem;      // 32x33 floats = 4.2 KB
    const float* W;
    unsigned short* Whi;
    int N, k0, n0;
    if (bid < 1792) {
        int idx = bid - 1024;                  // 768 blocks: 48 n-tiles x 16 k-tiles
        W = Wq; Whi = Wqh; N = NQKV_;
        n0 = (idx % 48) * 32; k0 = (idx / 48) * 32;
    } else {
        int idx = bid - 1792;                  // 256 blocks: 16 x 16
        W = Wo; Whi = Woh; N = DIM_;
        n0 = (idx % 16) * 32; k0 = (idx / 16) * 32;
    }
    const int c = t & 31, r8 = t >> 5;
    #pragma unroll
    for (int i = 0; i < 4; ++i) {
        int r = r8 + i * 8;
        tile[r][c] = W[(size_t)(k0 + r) * N + n0 + c];
    }
    __syncthreads();
    #pragma unroll
    for (int i = 0; i < 4; ++i) {
        int r = r8 + i * 8;                 // n offset
        Whi[(size_t)(n0 + r) * 512 + k0 + c] = f2h(tile[c][r]);   // Kd = 512
    }
}

// ---------------------------------------------------------------------------
// fp16 MFMA GEMM (unchanged from round 2).
// ---------------------------------------------------------------------------
template<int BM, int BN, int WM, int WN, int TERMS>
__global__ __launch_bounds__(256) void gemm_mfma(
    const unsigned short* __restrict__ Ahi, const unsigned short* __restrict__ Alo,
    const unsigned short* __restrict__ Wh,
    const float* __restrict__ bias, float* __restrict__ C,
    unsigned short* __restrict__ Qho, unsigned short* __restrict__ Kho,
    unsigned short* __restrict__ Vho,
    int N, int Kd, int mode)
{
    constexpr int TM = WM / 16, TN = WN / 16;
    constexpr int WAVES_N = BN / WN;
    __shared__ unsigned short Ah[2][BM][32];
    __shared__ unsigned short Al[TERMS == 2 ? 2 : 1][TERMS == 2 ? BM : 1][32];
    __shared__ unsigned short Bh[2][BN][32];

    const int t = threadIdx.x, lane = t & 63, wave = t >> 6;
    const int wm = (wave / WAVES_N) * WM, wn = (wave % WAVES_N) * WN;
    const int m0 = blockIdx.y * BM, n0 = blockIdx.x * BN;
    const int l15 = lane & 15, l4 = lane >> 4;

    const int srow = lane >> 2;          // 0..15
    const int scol = (lane & 3) * 8;     // 0,8,16,24

    float4v acc[TM][TN];
    #pragma unroll
    for (int i = 0; i < TM; ++i)
        #pragma unroll
        for (int j = 0; j < TN; ++j)
            #pragma unroll
            for (int r = 0; r < 4; ++r) acc[i][j][r] = 0.f;

    const int NK = Kd / 32;

    #pragma unroll
    for (int c = wave; c < BM / 16; c += 4) {
        size_t g = (size_t)(m0 + c * 16 + srow) * Kd + scol;
        load_lds16(&Ahi[g], &Ah[0][c * 16][0]);
        if constexpr (TERMS == 2) load_lds16(&Alo[g], &Al[0][c * 16][0]);
    }
    #pragma unroll
    for (int c = wave; c < BN / 16; c += 4) {
        size_t g = (size_t)(n0 + c * 16 + srow) * Kd + scol;
        load_lds16(&Wh[g], &Bh[0][c * 16][0]);
    }
    __syncthreads();

    for (int ks = 0; ks < NK; ++ks) {
        const int cur = ks & 1, nxt = cur ^ 1;

        if (ks + 1 < NK) {
            const int k1 = (ks + 1) * 32;
            #pragma unroll
            for (int c = wave; c < BM / 16; c += 4) {
                size_t g = (size_t)(m0 + c * 16 + srow) * Kd + k1 + scol;
                load_lds16(&Ahi[g], &Ah[nxt][c * 16][0]);
                if constexpr (TERMS == 2) load_lds16(&Alo[g], &Al[nxt][c * 16][0]);
            }
            #pragma unroll
            for (int c = wave; c < BN / 16; c += 4) {
                size_t g = (size_t)(n0 + c * 16 + srow) * Kd + k1 + scol;
                load_lds16(&Wh[g], &Bh[nxt][c * 16][0]);
            }
        }

        half8 fa_h[TM], fa_l[TM], fb[TN];
        #pragma unroll
        for (int im = 0; im < TM; ++im) {
            fa_h[im] = *(const half8*)&Ah[cur][wm + im * 16 + l15][l4 * 8];
            if constexpr (TERMS == 2)
                fa_l[im] = *(const half8*)&Al[cur][wm + im * 16 + l15][l4 * 8];
        }
        #pragma unroll
        for (int in = 0; in < TN; ++in)
            fb[in] = *(const half8*)&Bh[cur][wn + in * 16 + l15][l4 * 8];
        #pragma unroll
        for (int im = 0; im < TM; ++im)
            #pragma unroll
            for (int in = 0; in < TN; ++in) {
                acc[im][in] = __builtin_amdgcn_mfma_f32_16x16x32_f16(fa_h[im], fb[in], acc[im][in], 0, 0, 0);
                if constexpr (TERMS == 2)
                    acc[im][in] = __builtin_amdgcn_mfma_f32_16x16x32_f16(fa_l[im], fb[in], acc[im][in], 0, 0, 0);
            }

        __syncthreads();
    }

    // epilogue: D row = (lane>>4)*4 + reg, col = lane&15  [m89-verified layout]
    if (mode == 0) {
        #pragma unroll
        for (int in = 0; in < TN; ++in) {
            int n = n0 + wn + in * 16 + l15;
            float bv = bias[n];
            #pragma unroll
            for (int im = 0; im < TM; ++im) {
                int mb = m0 + wm + im * 16 + l4 * 4;
                #pragma unroll
                for (int r = 0; r < 4; ++r)
                    C[(size_t)(mb + r) * N + n] = acc[im][in][r] + bv;
            }
        }
    } else {
        #pragma unroll
        for (int in = 0; in < TN; ++in) {
            int n = n0 + wn + in * 16 + l15;
            int which = n >> 9, h = (n >> 6) & 7, d = n & 63;
            unsigned short* dst = (which == 0) ? Qho : (which == 1 ? Kho : Vho);
            float bv = bias[n];
            #pragma unroll
            for (int im = 0; im < TM; ++im) {
                int mb = m0 + wm + im * 16 + l4 * 4;
                #pragma unroll
                for (int r = 0; r < 4; ++r) {
                    int m = mb + r, b = m >> 11, s = m & 2047;
                    dst[(((size_t)b * H_ + h) * S_ + s) * HD_ + d] =
                        f2h(acc[im][in][r] + bv);
                }
            }
        }
    }
}

// ---------------------------------------------------------------------------
// Class-grouped attention — registers only, barrier-free, LDS-free.
// One wave = one chunk: up to 8 member q-rows of ONE route class (identical
// route rows). K/V gathers amortize across all 8 rows:
//   per wave: 1 route load + 8 K-gathers + 8 V-gathers + 8 Q-loads,
//   i.e. ~3 VMEM/row and ~16 gather lines/row (was 33 VMEM, 128 lines).
// kreg/vreg: lane(p=lane&7, jl=lane>>3) holds K[key=pass*8+jl] chunk p and
// V[key=i*8+p] chunk jl. Same score/softmax/PV swizzle as round 2, applied
// per member row; all reductions DPP over lane bits 0-2.
// ---------------------------------------------------------------------------
__global__ __launch_bounds__(256, 3) void attn_kernel(
    const unsigned short* __restrict__ Qh, const unsigned short* __restrict__ Kh,
    const unsigned short* __restrict__ Vh, const int* __restrict__ routes,
    const int* __restrict__ members, const int4* __restrict__ recs,
    const int* __restrict__ nchp,
    unsigned short* __restrict__ Oh)
{
    const int wv = threadIdx.x >> 6, lane = threadIdx.x & 63;
    const int p = lane & 7, jl = lane >> 3;

    const int unit = blockIdx.x * 4 + wv;     // [0, 8192)
    const int bh = unit & 15, cidx = unit >> 4;   // cidx in [0, 512)
    const int b = bh >> 3, h = bh & 7;

    const unsigned short* qbase = Qh + (size_t)bh * S_ * HD_;
    const unsigned short* kbase = Kh + (size_t)bh * S_ * HD_;
    const unsigned short* vbase = Vh + (size_t)bh * S_ * HD_;
    const int nch = nchp[0];

    for (int chunk = cidx; chunk < nch; chunk += 512) {
        const int4 rec = recs[chunk];
        const int leader = rec.x, mstart = rec.y, mcnt = rec.z;

        // all 64 route entries of the class, one per lane
        const int rl = routes[(size_t)leader * K_ + lane];

        int mrow[8];
        #pragma unroll
        for (int r = 0; r < 8; ++r)
            mrow[r] = members[mstart + (r < mcnt ? r : 0)];

        // K gather: kreg[pass] = K[key=pass*8+jl] chunk p (8 lines/instr)
        ushort8v kreg[8];
        #pragma unroll
        for (int pass = 0; pass < 8; ++pass) {
            int rk = __shfl(rl, pass * 8 + jl);
            kreg[pass] = *(const ushort8v*)&kbase[(size_t)rk * HD_ + p * 8];
        }
        #pragma unroll
        for (int i = 0; i < 8; ++i) asm volatile("" : "+v"(kreg[i]));

        // V gather (issued early, consumed after softmax):
        // vreg[i] = V[key=i*8+p] chunk jl
        ushort8v vreg[8];
        #pragma unroll
        for (int i = 0; i < 8; ++i) {
            int rv = __shfl(rl, i * 8 + p);
            vreg[i] = *(const ushort8v*)&vbase[(size_t)rv * HD_ + jl * 8];
        }
        #pragma unroll
        for (int i = 0; i < 8; ++i) asm volatile("" : "+v"(vreg[i]));

        // Q: all lanes hold chunk p of each member row (1-2 lines/instr)
        half2v q[8][4];
        #pragma unroll
        for (int r = 0; r < 8; ++r) {
            ushort8v qv = *(const ushort8v*)&qbase[(size_t)mrow[r] * HD_ + p * 8];
            __builtin_memcpy(&q[r][0], &qv, 16);
        }

        // phase 1: scores. After DPP-reduce over p and keep-at-pass==p,
        // lane L holds score[r] of key (L&7)*8 + (L>>3).
        float sc[8] = {0.f,0.f,0.f,0.f,0.f,0.f,0.f,0.f};
        #pragma unroll
        for (int pass = 0; pass < 8; ++pass) {
            half2v kp[4];
            __builtin_memcpy(kp, &kreg[pass], 16);
            #pragma unroll
            for (int r = 0; r < 8; ++r) {
                float pa = 0.f;
                #pragma unroll
                for (int i = 0; i < 4; ++i)
                    pa = __builtin_amdgcn_fdot2(q[r][i], kp[i], pa, false);
                pa = dpp_addf<0xB1>(pa);
                pa = dpp_addf<0x4E>(pa);
                pa = dpp_addf<0x141>(pa);
                sc[r] = (pass == p) ? pa : sc[r];
            }
        }

        // softmax per row (lane-permuted scores; softmax perm-invariant)
        float w[8];
        #pragma unroll
        for (int r = 0; r < 8; ++r) {
            float s = sc[r] * 0.125f;
            float m = s;
            m = dpp_maxf<0xB1>(m);  m = dpp_maxf<0x4E>(m);
            m = dpp_maxf<0x141>(m); m = dpp_maxf<0x140>(m);
            m = fmaxf(m, __shfl_xor(m, 16));
            m = fmaxf(m, __shfl_xor(m, 32));
            float e = __expf(s - m);
            float su = e;
            su = dpp_addf<0xB1>(su);  su = dpp_addf<0x4E>(su);
            su = dpp_addf<0x141>(su); su = dpp_addf<0x140>(su);
            su += __shfl_xor(su, 16);
            su += __shfl_xor(su, 32);
            w[r] = e / su;            // weight of key (lane&7)*8 + (lane>>3)
        }

        // convert V once (k/q registers dead by here)
        float vf[8][8];
        #pragma unroll
        for (int i = 0; i < 8; ++i)
            #pragma unroll
            for (int j = 0; j < 8; ++j) vf[i][j] = h2f(vreg[i][j]);

        // phase 2 per row: lane accumulates d-chunk jl over keys {i*8+p};
        // weight of key i*8+p lives at lane p*8+i. Output reduce over p
        // (bits 0-2) via DPP; lanes (p==0, jl) store the 128B row.
        #pragma unroll
        for (int r = 0; r < 8; ++r) {
            float ac[8] = {0.f,0.f,0.f,0.f,0.f,0.f,0.f,0.f};
            #pragma unroll
            for (int i = 0; i < 8; ++i) {
                float wj = __shfl(w[r], p * 8 + i);
                #pragma unroll
                for (int j = 0; j < 8; ++j) ac[j] += wj * vf[i][j];
            }
            #pragma unroll
            for (int j = 0; j < 8; ++j) {
                ac[j] = dpp_addf<0xB1>(ac[j]);
                ac[j] = dpp_addf<0x4E>(ac[j]);
                ac[j] = dpp_addf<0x141>(ac[j]);
            }
            if (p == 0 && r < mcnt) {
                ushort8v ho;
                #pragma unroll
                for (int j = 0; j < 8; ++j) ho[j] = f2h(ac[j]);
                *(ushort8v*)&Oh[((size_t)b * S_ + mrow[r]) * DIM_ + h * HD_ + jl * 8] = ho;
            }
        }
    }
}

// ---------------------------------------------------------------------------
// ws layout (bytes):
//   0    Q fp16 4MB | 8M K fp16 4MB | 16M V fp16 4MB
//   24M  x_h / attn fp16 4MB
//   32M  Wqkv_h fp16 1.5M | +1.5M Wout_h fp16 0.5M
//   34M  members int[2048] | +8K recs int4[2048] | +40K nChunks
// ---------------------------------------------------------------------------
extern "C" void kernel_launch(void* const* d_in, const int* in_sizes, int n_in,
                              void* d_out, int out_size, void* d_ws, size_t ws_size,
                              hipStream_t stream)
{
    const float* x      = (const float*)d_in[0];
    const float* Wqkv   = (const float*)d_in[1];
    const float* bqkv   = (const float*)d_in[2];
    const float* Wout   = (const float*)d_in[3];
    const float* bout   = (const float*)d_in[4];
    const int*   routes = (const int*)d_in[5];
    float* out = (float*)d_out;

    char* w = (char*)d_ws;
    unsigned short* Qh = (unsigned short*)(w);
    unsigned short* Kh = (unsigned short*)(w + (8u << 20));
    unsigned short* Vh = (unsigned short*)(w + (16u << 20));
    unsigned short* xh = (unsigned short*)(w + (24u << 20));
    unsigned short* ah = xh;   // aliased: free after qkv gemm
    unsigned short* wqh = (unsigned short*)(w + (32u << 20));
    unsigned short* woh = (unsigned short*)(w + (32u << 20) + 1572864u);
    int*  members = (int*)(w + (34u << 20));
    int4* recs    = (int4*)(w + (34u << 20) + 8192u);
    int*  nchp    = (int*)(w + (34u << 20) + 8192u + 32768u);

    dim3 blk(256);

    // fused prep: x-convert (1024) + W transposes (1024) + grouping (1 block)
    prep_all<<<dim3(2049), blk, 0, stream>>>(x, xh, Wqkv, wqh, Wout, woh,
                                             routes, members, recs, nchp);

    // qkv: M=4096, N=1536, K=512 -> 16x32 = 512 blocks, 1-term A
    gemm_mfma<128, 96, 64, 48, 1><<<dim3(NQKV_ / 96, M_ / 128), blk, 0, stream>>>(
        xh, nullptr, wqh, bqkv, nullptr, Qh, Kh, Vh, NQKV_, DIM_, 1);

    attn_kernel<<<dim3(2048), blk, 0, stream>>>(Qh, Kh, Vh, routes,
                                                members, recs, nchp, ah);

    // out-proj: M=4096, N=512, K=512 -> 8x64 = 512 blocks, 1-term A
    gemm_mfma<64, 64, 32, 32, 1><<<dim3(DIM_ / 64, M_ / 64), blk, 0, stream>>>(
        ah, nullptr, woh, bout, out, nullptr, nullptr, nullptr, DIM_, DIM_, 0);
}

// Round 5
// 118.135 us; speedup vs baseline: 1.2800x; 1.1233x over previous
//
#include <hip/hip_runtime.h>
#include <math.h>

// CantorAttention: B=2, S=2048, DIM=512, H=8, HD=64, K=64
#define B_    2
#define S_    2048
#define DIM_  512
#define H_    8
#define HD_   64
#define K_    64
#define M_    (B_ * S_)          // 4096
#define NQKV_ (3 * DIM_)         // 1536

typedef __attribute__((ext_vector_type(8))) _Float16       half8;     // mfma A/B frag (8 f16)
typedef __attribute__((ext_vector_type(8))) unsigned short ushort8v;  // 16B move
typedef __attribute__((ext_vector_type(4))) float          float4v;   // mfma C/D frag

union H8 { half8 h; ushort8v u; unsigned int w[4]; };

// ---- fp16 helpers ----------------------------------------------------------
__device__ __forceinline__ unsigned short f2h(float f) {
    _Float16 h = (_Float16)f;
    unsigned short u; __builtin_memcpy(&u, &h, 2); return u;
}
__device__ __forceinline__ unsigned int pkrtz(float a, float b) {
    auto r = __builtin_amdgcn_cvt_pkrtz(a, b);   // __fp16x2: D.lo=a, D.hi=b
    unsigned int u; __builtin_memcpy(&u, &r, 4); return u;
}

// async 16B global -> LDS (lane l lands at ldsbase + l*16; per-lane global src)
__device__ __forceinline__ void load_lds16(const unsigned short* g, unsigned short* l) {
    __builtin_amdgcn_global_load_lds(
        (const __attribute__((address_space(1))) void*)g,
        (__attribute__((address_space(3))) void*)l, 16, 0, 0);
}

// ---------------------------------------------------------------------------
// prep_all: one kernel, block-range partitioned.
//   [0,1024): convert x fp32 -> xh fp16
//   [1024,1792): transpose Wqkv -> fp16 [N][Kd]
//   [1792,2048): transpose Wout -> fp16
//   [2048]: route class grouping (16-member chunks for the MFMA attn).
//           routes[s][0] is a perfect class key (self-distance 0 + stable
//           argsort) — validated by round-1/3 passing.
// ---------------------------------------------------------------------------
__global__ __launch_bounds__(256) void prep_all(
    const float* __restrict__ X, unsigned short* __restrict__ Xh,
    const float* __restrict__ Wq, unsigned short* __restrict__ Wqh,
    const float* __restrict__ Wo, unsigned short* __restrict__ Woh,
    const int* __restrict__ routes, int* __restrict__ members,
    int4* __restrict__ recs, int* __restrict__ nchp)
{
    __shared__ int smem[2048 * 3 + 256];
    const int bid = blockIdx.x, t = threadIdx.x;

    if (bid < 1024) {
        size_t i = ((size_t)bid * 256 + t) * 8;
        float4 a = *(const float4*)&X[i];
        float4 b = *(const float4*)&X[i + 4];
        float f[8] = {a.x, a.y, a.z, a.w, b.x, b.y, b.z, b.w};
        ushort8v h;
        #pragma unroll
        for (int j = 0; j < 8; ++j) h[j] = f2h(f[j]);
        *(ushort8v*)&Xh[i] = h;
        return;
    }

    if (bid == 2048) {
        int* cnt  = smem;            // [2048]
        int* base = smem + 2048;     // [2048]
        int* cur  = smem + 4096;     // [2048]
        int* ps   = smem + 6144;     // [256]
        for (int i = t; i < 2048; i += 256) cnt[i] = 0;
        __syncthreads();
        int lead[8];
        #pragma unroll
        for (int i = 0; i < 8; ++i) {
            lead[i] = routes[(size_t)(i * 256 + t) * K_];
            atomicAdd(&cnt[lead[i]], 1);
        }
        __syncthreads();
        int loc[8], sum = 0;
        #pragma unroll
        for (int i = 0; i < 8; ++i) { loc[i] = sum; sum += cnt[t * 8 + i]; }
        ps[t] = sum;
        __syncthreads();
        for (int off = 1; off < 256; off <<= 1) {
            int v = ps[t];
            if (t >= off) v += ps[t - off];
            __syncthreads(); ps[t] = v; __syncthreads();
        }
        const int excl = ps[t] - sum;
        #pragma unroll
        for (int i = 0; i < 8; ++i) { base[t * 8 + i] = excl + loc[i]; cur[t * 8 + i] = 0; }
        __syncthreads();
        #pragma unroll
        for (int i = 0; i < 8; ++i) {
            int s = i * 256 + t;
            members[base[lead[i]] + atomicAdd(&cur[lead[i]], 1)] = s;
        }
        // chunk records: ceil(cnt/16) per class (16-member chunks)
        int cloc[8], csum = 0;
        #pragma unroll
        for (int i = 0; i < 8; ++i) { cloc[i] = csum; csum += (cnt[t * 8 + i] + 15) >> 4; }
        __syncthreads();
        ps[t] = csum;
        __syncthreads();
        for (int off = 1; off < 256; off <<= 1) {
            int v = ps[t];
            if (t >= off) v += ps[t - off];
            __syncthreads(); ps[t] = v; __syncthreads();
        }
        const int cexcl = ps[t] - csum;
        #pragma unroll
        for (int i = 0; i < 8; ++i) {
            const int c = t * 8 + i, n = cnt[c];
            int w0 = cexcl + cloc[i];
            for (int k2 = 0; k2 * 16 < n; ++k2) {
                int rem = n - k2 * 16;
                recs[w0 + k2] = make_int4(c, base[c] + k2 * 16, rem < 16 ? rem : 16, 0);
            }
        }
        if (t == 255) nchp[0] = ps[255];
        return;
    }

    float (*tile)[33] = (float (*)[33])smem;
    const float* W;
    unsigned short* Whi;
    int N, k0, n0;
    if (bid < 1792) {
        int idx = bid - 1024;                  // 768 blocks: 48 x 16
        W = Wq; Whi = Wqh; N = NQKV_;
        n0 = (idx % 48) * 32; k0 = (idx / 48) * 32;
    } else {
        int idx = bid - 1792;                  // 256 blocks: 16 x 16
        W = Wo; Whi = Woh; N = DIM_;
        n0 = (idx % 16) * 32; k0 = (idx / 16) * 32;
    }
    const int c = t & 31, r8 = t >> 5;
    #pragma unroll
    for (int i = 0; i < 4; ++i) {
        int r = r8 + i * 8;
        tile[r][c] = W[(size_t)(k0 + r) * N + n0 + c];
    }
    __syncthreads();
    #pragma unroll
    for (int i = 0; i < 4; ++i) {
        int r = r8 + i * 8;
        Whi[(size_t)(n0 + r) * 512 + k0 + c] = f2h(tile[c][r]);   // Kd = 512
    }
}

// ---------------------------------------------------------------------------
// fp16 MFMA GEMM (as round 3; mode 1 folds SCALE=0.125 into Q).
// ---------------------------------------------------------------------------
template<int BM, int BN, int WM, int WN, int TERMS>
__global__ __launch_bounds__(256) void gemm_mfma(
    const unsigned short* __restrict__ Ahi, const unsigned short* __restrict__ Alo,
    const unsigned short* __restrict__ Wh,
    const float* __restrict__ bias, float* __restrict__ C,
    unsigned short* __restrict__ Qho, unsigned short* __restrict__ Kho,
    unsigned short* __restrict__ Vho,
    int N, int Kd, int mode)
{
    constexpr int TM = WM / 16, TN = WN / 16;
    constexpr int WAVES_N = BN / WN;
    __shared__ unsigned short Ah[2][BM][32];
    __shared__ unsigned short Al[TERMS == 2 ? 2 : 1][TERMS == 2 ? BM : 1][32];
    __shared__ unsigned short Bh[2][BN][32];

    const int t = threadIdx.x, lane = t & 63, wave = t >> 6;
    const int wm = (wave / WAVES_N) * WM, wn = (wave % WAVES_N) * WN;
    const int m0 = blockIdx.y * BM, n0 = blockIdx.x * BN;
    const int l15 = lane & 15, l4 = lane >> 4;

    const int srow = lane >> 2;
    const int scol = (lane & 3) * 8;

    float4v acc[TM][TN];
    #pragma unroll
    for (int i = 0; i < TM; ++i)
        #pragma unroll
        for (int j = 0; j < TN; ++j)
            #pragma unroll
            for (int r = 0; r < 4; ++r) acc[i][j][r] = 0.f;

    const int NK = Kd / 32;

    #pragma unroll
    for (int c = wave; c < BM / 16; c += 4) {
        size_t g = (size_t)(m0 + c * 16 + srow) * Kd + scol;
        load_lds16(&Ahi[g], &Ah[0][c * 16][0]);
        if constexpr (TERMS == 2) load_lds16(&Alo[g], &Al[0][c * 16][0]);
    }
    #pragma unroll
    for (int c = wave; c < BN / 16; c += 4) {
        size_t g = (size_t)(n0 + c * 16 + srow) * Kd + scol;
        load_lds16(&Wh[g], &Bh[0][c * 16][0]);
    }
    __syncthreads();

    for (int ks = 0; ks < NK; ++ks) {
        const int cur = ks & 1, nxt = cur ^ 1;

        if (ks + 1 < NK) {
            const int k1 = (ks + 1) * 32;
            #pragma unroll
            for (int c = wave; c < BM / 16; c += 4) {
                size_t g = (size_t)(m0 + c * 16 + srow) * Kd + k1 + scol;
                load_lds16(&Ahi[g], &Ah[nxt][c * 16][0]);
                if constexpr (TERMS == 2) load_lds16(&Alo[g], &Al[nxt][c * 16][0]);
            }
            #pragma unroll
            for (int c = wave; c < BN / 16; c += 4) {
                size_t g = (size_t)(n0 + c * 16 + srow) * Kd + k1 + scol;
                load_lds16(&Wh[g], &Bh[nxt][c * 16][0]);
            }
        }

        half8 fa_h[TM], fa_l[TM], fb[TN];
        #pragma unroll
        for (int im = 0; im < TM; ++im) {
            fa_h[im] = *(const half8*)&Ah[cur][wm + im * 16 + l15][l4 * 8];
            if constexpr (TERMS == 2)
                fa_l[im] = *(const half8*)&Al[cur][wm + im * 16 + l15][l4 * 8];
        }
        #pragma unroll
        for (int in = 0; in < TN; ++in)
            fb[in] = *(const half8*)&Bh[cur][wn + in * 16 + l15][l4 * 8];
        #pragma unroll
        for (int im = 0; im < TM; ++im)
            #pragma unroll
            for (int in = 0; in < TN; ++in) {
                acc[im][in] = __builtin_amdgcn_mfma_f32_16x16x32_f16(fa_h[im], fb[in], acc[im][in], 0, 0, 0);
                if constexpr (TERMS == 2)
                    acc[im][in] = __builtin_amdgcn_mfma_f32_16x16x32_f16(fa_l[im], fb[in], acc[im][in], 0, 0, 0);
            }

        __syncthreads();
    }

    // epilogue: D row = (lane>>4)*4 + reg, col = lane&15  [m89-verified layout]
    if (mode == 0) {
        #pragma unroll
        for (int in = 0; in < TN; ++in) {
            int n = n0 + wn + in * 16 + l15;
            float bv = bias[n];
            #pragma unroll
            for (int im = 0; im < TM; ++im) {
                int mb = m0 + wm + im * 16 + l4 * 4;
                #pragma unroll
                for (int r = 0; r < 4; ++r)
                    C[(size_t)(mb + r) * N + n] = acc[im][in][r] + bv;
            }
        }
    } else {
        #pragma unroll
        for (int in = 0; in < TN; ++in) {
            int n = n0 + wn + in * 16 + l15;
            int which = n >> 9, h = (n >> 6) & 7, d = n & 63;
            unsigned short* dst = (which == 0) ? Qho : (which == 1 ? Kho : Vho);
            float bv = bias[n];
            float scl = (which == 0) ? 0.125f : 1.0f;   // fold attention SCALE into Q
            #pragma unroll
            for (int im = 0; im < TM; ++im) {
                int mb = m0 + wm + im * 16 + l4 * 4;
                #pragma unroll
                for (int r = 0; r < 4; ++r) {
                    int m = mb + r, b = m >> 11, s = m & 2047;
                    dst[(((size_t)b * H_ + h) * S_ + s) * HD_ + d] =
                        f2h((acc[im][in][r] + bv) * scl);
                }
            }
        }
    }
}

// ---------------------------------------------------------------------------
// MFMA class-grouped attention. One wave = one chunk of <=16 member rows of
// one route class (identical route rows). Round-3 post-mortem: attn was
// VALU-instruction-bound (~300 eff. instr/row), not gather-bound. MFMA tile:
//   scores: A=K(gathered frags), B=Q(member frags) -> S[key][m];
//           softmax over keys = in-register 16 + shfl_xor(16,32).
//   P-redistribution C-layout->A-layout: 16 bpermutes + cndmask by g>>1.
//   PV: A=P, B=V-columns from wave-private LDS (global_load_lds staged,
//       source-chunk XOR pre-swizzle per rule-21 so column reads are ~2-way).
// No barriers (wave-private LDS); explicit vmcnt(0) before the LDS column
// reads covers the V DMA. ~30 VALU + 1 MFMA + ~2 VMEM per row.
// ---------------------------------------------------------------------------
__global__ __launch_bounds__(256, 4) void attn_kernel(
    const unsigned short* __restrict__ Qh, const unsigned short* __restrict__ Kh,
    const unsigned short* __restrict__ Vh, const int* __restrict__ routes,
    const int* __restrict__ members, const int4* __restrict__ recs,
    const int* __restrict__ nchp, unsigned short* __restrict__ Oh)
{
    __shared__ unsigned short VldsAll[4][4096];   // 8KB per wave, [key][d] f16
    const int wv = threadIdx.x >> 6, lane = threadIdx.x & 63;
    unsigned short* Vlds = VldsAll[wv];
    const int g = lane >> 4, m16 = lane & 15;

    const int unit = blockIdx.x * 4 + wv;         // [0, 8192)
    const int bh = unit & 15, cidx = unit >> 4;   // cidx in [0, 512)
    const int b = bh >> 3, h = bh & 7;

    const unsigned short* qbase = Qh + (size_t)bh * S_ * HD_;
    const unsigned short* kbase = Kh + (size_t)bh * S_ * HD_;
    const unsigned short* vbase = Vh + (size_t)bh * S_ * HD_;
    const int nch = nchp[0];

    for (int chunk = cidx; chunk < nch; chunk += 512) {
        const int4 rec = recs[chunk];
        const int leader = rec.x, mstart = rec.y, mcnt = rec.z;

        const int rl = routes[(size_t)leader * K_ + lane];   // route entry per lane
        const int mm = members[mstart + (m16 < mcnt ? m16 : mcnt - 1)];

        // ---- V -> wave-private LDS (linear dest; source chunk pre-swizzled:
        // dest [key][c] holds V[key][c ^ (key>>3)]) ----
        #pragma unroll
        for (int i = 0; i < 8; ++i) {
            int rv = __shfl(rl, i * 8 + (lane >> 3));
            int sc = (lane & 7) ^ i;
            load_lds16(&vbase[(size_t)rv * HD_ + sc * 8], Vlds + i * 512);
        }

        // ---- K A-frags: row=key-in-tile (m16), k=d chunk g*8 + 32s ----
        H8 ka[4][2];
        #pragma unroll
        for (int tt = 0; tt < 4; ++tt) {
            int rt = __shfl(rl, tt * 16 + m16);
            const unsigned short* kr = &kbase[(size_t)rt * HD_];
            ka[tt][0].u = *(const ushort8v*)(kr + g * 8);
            ka[tt][1].u = *(const ushort8v*)(kr + 32 + g * 8);
        }
        // ---- Q B-frags: col=m16 (own member row; Q pre-scaled by 0.125) ----
        const unsigned short* qr = &qbase[(size_t)mm * HD_];
        H8 qb0, qb1;
        qb0.u = *(const ushort8v*)(qr + g * 8);
        qb1.u = *(const ushort8v*)(qr + 32 + g * 8);

        // ---- scores: D[key=16t+4g+r][m=m16] ----
        float4v acc[4];
        #pragma unroll
        for (int tt = 0; tt < 4; ++tt) {
            #pragma unroll
            for (int r = 0; r < 4; ++r) acc[tt][r] = 0.f;
        }
        #pragma unroll
        for (int tt = 0; tt < 4; ++tt) {
            acc[tt] = __builtin_amdgcn_mfma_f32_16x16x32_f16(ka[tt][0].h, qb0.h, acc[tt], 0, 0, 0);
            acc[tt] = __builtin_amdgcn_mfma_f32_16x16x32_f16(ka[tt][1].h, qb1.h, acc[tt], 0, 0, 0);
        }

        // ---- softmax over 64 keys for this lane's m ----
        float mx = acc[0][0];
        #pragma unroll
        for (int tt = 0; tt < 4; ++tt)
            #pragma unroll
            for (int r = 0; r < 4; ++r) mx = fmaxf(mx, acc[tt][r]);
        mx = fmaxf(mx, __shfl_xor(mx, 16));
        mx = fmaxf(mx, __shfl_xor(mx, 32));
        float ew[4][4], su = 0.f;
        #pragma unroll
        for (int tt = 0; tt < 4; ++tt)
            #pragma unroll
            for (int r = 0; r < 4; ++r) { ew[tt][r] = __expf(acc[tt][r] - mx); su += ew[tt][r]; }
        su += __shfl_xor(su, 16);
        su += __shfl_xor(su, 32);
        const float rinv = __builtin_amdgcn_rcpf(su);

        unsigned int whu[4][2];
        #pragma unroll
        for (int tt = 0; tt < 4; ++tt) {
            whu[tt][0] = pkrtz(ew[tt][0] * rinv, ew[tt][1] * rinv);
            whu[tt][1] = pkrtz(ew[tt][2] * rinv, ew[tt][3] * rinv);
        }

        // ---- P redistribution: C-layout (key=16t+4g+r @ col m) ->
        // A-frag (row m=m16, k=key 32s+8g+j). Source lane (g'<<4)|m16 with
        // g' = 2(g&1)+(j>>2); t' = 2s+(g>>1) selected by cndmask. ----
        const int A0 = (((g & 1) << 5) | m16) * 4;
        const int A1 = A0 + 64;
        const bool ghi = (g >> 1) != 0;
        H8 pa[2];
        #pragma unroll
        for (int s = 0; s < 2; ++s) {
            unsigned int l0a = (unsigned int)__builtin_amdgcn_ds_bpermute(A0, (int)whu[2 * s][0]);
            unsigned int l0b = (unsigned int)__builtin_amdgcn_ds_bpermute(A0, (int)whu[2 * s + 1][0]);
            unsigned int h0a = (unsigned int)__builtin_amdgcn_ds_bpermute(A0, (int)whu[2 * s][1]);
            unsigned int h0b = (unsigned int)__builtin_amdgcn_ds_bpermute(A0, (int)whu[2 * s + 1][1]);
            unsigned int l1a = (unsigned int)__builtin_amdgcn_ds_bpermute(A1, (int)whu[2 * s][0]);
            unsigned int l1b = (unsigned int)__builtin_amdgcn_ds_bpermute(A1, (int)whu[2 * s + 1][0]);
            unsigned int h1a = (unsigned int)__builtin_amdgcn_ds_bpermute(A1, (int)whu[2 * s][1]);
            unsigned int h1b = (unsigned int)__builtin_amdgcn_ds_bpermute(A1, (int)whu[2 * s + 1][1]);
            pa[s].w[0] = ghi ? l0b : l0a;   // j=0,1  (r'=0,1 from A0)
            pa[s].w[1] = ghi ? h0b : h0a;   // j=2,3  (r'=2,3 from A0)
            pa[s].w[2] = ghi ? l1b : l1a;   // j=4,5  (r'=0,1 from A1)
            pa[s].w[3] = ghi ? h1b : h1a;   // j=6,7  (r'=2,3 from A1)
        }

        // member rows for the store (D row m = g*4+r)
        int mr[4];
        #pragma unroll
        for (int r = 0; r < 4; ++r)
            mr[r] = __builtin_amdgcn_ds_bpermute((g * 4 + r) * 4, mm);

        // V DMA must have landed before the column reads
        asm volatile("s_waitcnt vmcnt(0)" ::: "memory");
        __builtin_amdgcn_sched_barrier(0);

        // ---- PV per 16-wide d-block: B col = d (m16), k = key ----
        #pragma unroll
        for (int dblk = 0; dblk < 4; ++dblk) {
            H8 vb[2];
            #pragma unroll
            for (int s = 0; s < 2; ++s) {
                const char* vp = (const char*)Vlds + (s * 32 + g * 8) * 128 +
                    (((dblk * 16 + m16) * 2) ^ ((((s * 4 + g) & 7)) << 4));
                #pragma unroll
                for (int j = 0; j < 8; ++j)
                    vb[s].u[j] = *(const unsigned short*)(vp + j * 128);
            }
            float4v o;
            o[0] = 0.f; o[1] = 0.f; o[2] = 0.f; o[3] = 0.f;
            o = __builtin_amdgcn_mfma_f32_16x16x32_f16(pa[0].h, vb[0].h, o, 0, 0, 0);
            o = __builtin_amdgcn_mfma_f32_16x16x32_f16(pa[1].h, vb[1].h, o, 0, 0, 0);
            #pragma unroll
            for (int r = 0; r < 4; ++r) {
                if (g * 4 + r < mcnt) {
                    size_t oi = ((size_t)b * S_ + mr[r]) * DIM_ + h * HD_ + dblk * 16 + m16;
                    Oh[oi] = f2h(o[r]);
                }
            }
        }
    }
}

// ---------------------------------------------------------------------------
// ws layout (bytes):
//   0    Q fp16 4MB | 8M K fp16 4MB | 16M V fp16 4MB
//   24M  x_h / attn fp16 4MB
//   32M  Wqkv_h fp16 1.5M | +1.5M Wout_h fp16 0.5M
//   34M  members int[2048] | +8K recs int4[2048] | +40K nChunks
// ---------------------------------------------------------------------------
extern "C" void kernel_launch(void* const* d_in, const int* in_sizes, int n_in,
                              void* d_out, int out_size, void* d_ws, size_t ws_size,
                              hipStream_t stream)
{
    const float* x      = (const float*)d_in[0];
    const float* Wqkv   = (const float*)d_in[1];
    const float* bqkv   = (const float*)d_in[2];
    const float* Wout   = (const float*)d_in[3];
    const float* bout   = (const float*)d_in[4];
    const int*   routes = (const int*)d_in[5];
    float* out = (float*)d_out;

    char* w = (char*)d_ws;
    unsigned short* Qh = (unsigned short*)(w);
    unsigned short* Kh = (unsigned short*)(w + (8u << 20));
    unsigned short* Vh = (unsigned short*)(w + (16u << 20));
    unsigned short* xh = (unsigned short*)(w + (24u << 20));
    unsigned short* ah = xh;   // aliased: free after qkv gemm
    unsigned short* wqh = (unsigned short*)(w + (32u << 20));
    unsigned short* woh = (unsigned short*)(w + (32u << 20) + 1572864u);
    int*  members = (int*)(w + (34u << 20));
    int4* recs    = (int4*)(w + (34u << 20) + 8192u);
    int*  nchp    = (int*)(w + (34u << 20) + 8192u + 32768u);

    dim3 blk(256);

    // fused prep: x-convert (1024) + W transposes (1024) + grouping (1 block)
    prep_all<<<dim3(2049), blk, 0, stream>>>(x, xh, Wqkv, wqh, Wout, woh,
                                             routes, members, recs, nchp);

    // qkv: M=4096, N=1536, K=512 -> 16x32 = 512 blocks, 1-term A
    gemm_mfma<128, 96, 64, 48, 1><<<dim3(NQKV_ / 96, M_ / 128), blk, 0, stream>>>(
        xh, nullptr, wqh, bqkv, nullptr, Qh, Kh, Vh, NQKV_, DIM_, 1);

    attn_kernel<<<dim3(2048), blk, 0, stream>>>(Qh, Kh, Vh, routes,
                                                members, recs, nchp, ah);

    // out-proj: M=4096, N=512, K=512 -> 8x64 = 512 blocks, 1-term A
    gemm_mfma<64, 64, 32, 32, 1><<<dim3(DIM_ / 64, M_ / 64), blk, 0, stream>>>(
        ah, nullptr, woh, bout, out, nullptr, nullptr, nullptr, DIM_, DIM_, 0);
}